// Round 2
// baseline (549.668 us; speedup 1.0000x reference)
//
#include <hip/hip_runtime.h>
#include <hip/hip_fp16.h>
#include <stdint.h>

#define BB 512
#define TT 1024
#define II 15
#define HH 64
#define OO 11

typedef _Float16 half8 __attribute__((ext_vector_type(8)));
typedef float floatx4 __attribute__((ext_vector_type(4)));

// Pack x[b][t][0..14] f32 -> xp[b][t][0..15] f16 with slot 15 = 1.0 (bias lane).
// Gives the recurrence aligned 16B half8 loads and pre-converted f16.
__global__ __launch_bounds__(256) void xpack_kernel(
    const float* __restrict__ x, _Float16* __restrict__ xp)
{
    int idx = blockIdx.x * 256 + threadIdx.x;   // over B*T*16
    int i = idx & 15;
    int bt = idx >> 4;
    float v = (i < II) ? x[(size_t)bt * II + i] : 1.0f;
    xp[idx] = (_Float16)v;
}

// MFMA recurrence: one wave per 16-batch group g. M=16 batches, N=64 h_out
// (4 blocks of 16), K=64 h_in (2 halves) + fused input proj (K slots 0..14 = x,
// slot 15 = 1.0 * combined bias). 12 MFMAs/step. C-layout -> A-layout transform
// via LDS (row pad 72 halfwords -> 2-way banks = free). Single wave: no barriers.
template<bool XP>
__global__ __launch_bounds__(64) void rnn_rec(
    const float* __restrict__ x, const _Float16* __restrict__ xpk,
    const float* __restrict__ W_ih, const float* __restrict__ b_ih,
    const float* __restrict__ W_hh, const float* __restrict__ b_hh,
    _Float16* __restrict__ hs, float* __restrict__ h_last)
{
    __shared__ __align__(16) _Float16 hbuf[16 * 72];
    const int lane = threadIdx.x;
    const int col = lane & 15;
    const int quad = lane >> 4;
    const int g = blockIdx.x;

    // B-frags for W_hh: bw[nb][hk][j] = W_hh[nb*16+col][hk*32 + quad*8 + j]
    half8 bw[4][2];
#pragma unroll
    for (int nb = 0; nb < 4; ++nb)
#pragma unroll
        for (int hk = 0; hk < 2; ++hk) {
            const float* wp = W_hh + (nb * 16 + col) * HH + hk * 32 + quad * 8;
            half8 f;
#pragma unroll
            for (int j = 0; j < 8; ++j) f[j] = (_Float16)wp[j];
            bw[nb][hk] = f;
        }

    // B-frags for input proj: k<15 -> W_ih[n][k]; k==15 -> b_ih[n]+b_hh[n]; else 0
    half8 bxi[4];
#pragma unroll
    for (int nb = 0; nb < 4; ++nb) {
        const int n = nb * 16 + col;
        half8 f;
#pragma unroll
        for (int j = 0; j < 8; ++j) {
            const int k = quad * 8 + j;
            float v = 0.0f;
            if (k < II) v = W_ih[n * II + k];
            else if (k == II) v = b_ih[n] + b_hh[n];
            f[j] = (_Float16)v;
        }
        bxi[nb] = f;
    }

    const _Float16* xprow = xpk
        ? (xpk + (size_t)(g * 16 + col) * TT * 16 + (size_t)(quad & 1) * 8)
        : nullptr;
    const float* xrow = x + (size_t)(g * 16 + col) * TT * II;

    auto load_ax = [&](int t) -> half8 {
        half8 a;
        if (XP) {
            a = *(const half8*)(xprow + (size_t)t * 16);
            if (quad >= 2) {  // k >= 16: zero contribution
                half8 z = {0, 0, 0, 0, 0, 0, 0, 0};
                a = z;
            }
        } else {
            const float* xr = xrow + (size_t)t * II;
            float xf[8];
#pragma unroll
            for (int j = 0; j < 8; ++j) {
                int i = quad * 8 + j;
                xf[j] = xr[i < II ? i : II - 1];   // clamp keeps loads in-bounds
            }
#pragma unroll
            for (int j = 0; j < 8; ++j) {
                int k = quad * 8 + j;
                a[j] = (k < II) ? (_Float16)xf[j]
                                : ((k == II) ? (_Float16)1.0f : (_Float16)0.0f);
            }
        }
        return a;
    };

    half8 af0 = {0, 0, 0, 0, 0, 0, 0, 0};   // h(-1) = 0
    half8 af1 = {0, 0, 0, 0, 0, 0, 0, 0};

    // 4-deep x prefetch pipeline (~960 cyc ahead > ~900 cyc HBM latency)
    half8 axq[4];
#pragma unroll
    for (int u = 0; u < 4; ++u) axq[u] = load_ax(u);

    _Float16* hsg = hs + (size_t)g * TT * 16 * HH + (size_t)col * HH + quad * 8;

    for (int tb = 0; tb < TT; tb += 4) {
#pragma unroll
        for (int u = 0; u < 4; ++u) {
            const int t = tb + u;
            floatx4 acc[4];
#pragma unroll
            for (int nb = 0; nb < 4; ++nb) {
                floatx4 a = {0.0f, 0.0f, 0.0f, 0.0f};
                a = __builtin_amdgcn_mfma_f32_16x16x32_f16(axq[u], bxi[nb], a, 0, 0, 0);
                a = __builtin_amdgcn_mfma_f32_16x16x32_f16(af0, bw[nb][0], a, 0, 0, 0);
                a = __builtin_amdgcn_mfma_f32_16x16x32_f16(af1, bw[nb][1], a, 0, 0, 0);
                acc[nb] = a;
            }
            {   // prefetch x for t+4
                int tp = t + 4;
                if (tp > TT - 1) tp = TT - 1;
                axq[u] = load_ax(tp);
            }
            // epilogue: relu, cvt f16, write C-layout into LDS [m][n] (pad 72)
#pragma unroll
            for (int nb = 0; nb < 4; ++nb)
#pragma unroll
                for (int r = 0; r < 4; ++r) {
                    float v = fmaxf(acc[nb][r], 0.0f);
                    hbuf[(quad * 4 + r) * 72 + nb * 16 + col] = (_Float16)v;
                }
            // read back A-layout fragments for next step
            af0 = *(const half8*)&hbuf[col * 72 + quad * 8];
            af1 = *(const half8*)&hbuf[col * 72 + 32 + quad * 8];
            // store h(t) to global in A-layout: hs[g][t][m][k], 2KB/wave contiguous
            _Float16* hp = hsg + (size_t)t * (16 * HH);
            *(half8*)hp = af0;
            *(half8*)(hp + 32) = af1;
        }
    }
    // h_last (fp32 output) from final A-frags
    float* hlp = h_last + (size_t)(g * 16 + col) * HH + quad * 8;
#pragma unroll
    for (int j = 0; j < 8; ++j) {
        hlp[j] = (float)af0[j];
        hlp[32 + j] = (float)af1[j];
    }
}

// Decoder: one MFMA tile per wave. Tile = (g,t): 16 rows (m = batch within
// group) x K=64, contiguous 2KB in hs. 32768 waves -> latency well amortized.
__global__ __launch_bounds__(256) void rnn_decode(
    const _Float16* __restrict__ hs, const float* __restrict__ W_dec,
    const float* __restrict__ b_dec, float* __restrict__ out)
{
    __shared__ __align__(16) _Float16 wl[16 * HH];
    const int tid = threadIdx.x;
    for (int i = tid; i < 16 * HH; i += 256)
        wl[i] = (_Float16)((i < OO * HH) ? W_dec[i] : 0.0f);
    __syncthreads();

    const int lane = tid & 63;
    const int wid  = tid >> 6;
    const int col  = lane & 15;
    const int quad = lane >> 4;
    const float bd = (col < OO) ? b_dec[col] : 0.0f;

    half8 bf0 = *(const half8*)&wl[col * HH + quad * 8];
    half8 bf1 = *(const half8*)&wl[col * HH + 32 + quad * 8];

    const int gid = blockIdx.x * 4 + wid;   // 0..32767 = g*1024 + t
    const int g = gid >> 10;
    const int t = gid & 1023;

    const _Float16* ap = hs + (((size_t)g * TT + t) * 16 + col) * HH + quad * 8;
    half8 a0 = *(const half8*)ap;
    half8 a1 = *(const half8*)(ap + 32);

    floatx4 acc = {0.0f, 0.0f, 0.0f, 0.0f};
    acc = __builtin_amdgcn_mfma_f32_16x16x32_f16(a0, bf0, acc, 0, 0, 0);
    acc = __builtin_amdgcn_mfma_f32_16x16x32_f16(a1, bf1, acc, 0, 0, 0);

    if (col < OO) {
#pragma unroll
        for (int r = 0; r < 4; ++r) {
            const size_t b = (size_t)g * 16 + quad * 4 + r;
            out[(b * TT + t) * OO + col] = fmaxf(acc[r] + bd, 0.0f);
        }
    }
}

extern "C" void kernel_launch(void* const* d_in, const int* in_sizes, int n_in,
                              void* d_out, int out_size, void* d_ws, size_t ws_size,
                              hipStream_t stream) {
    const float* x     = (const float*)d_in[0];
    const float* W_ih  = (const float*)d_in[1];
    const float* b_ih  = (const float*)d_in[2];
    const float* W_hh  = (const float*)d_in[3];
    const float* b_hh  = (const float*)d_in[4];
    const float* W_dec = (const float*)d_in[5];
    const float* b_dec = (const float*)d_in[6];

    float* out    = (float*)d_out;
    float* h_last = out + (size_t)BB * TT * OO;   // second tuple output

    _Float16* hs = (_Float16*)d_ws;                          // 64 MiB
    const size_t hs_bytes = (size_t)BB * TT * HH * sizeof(_Float16);
    const size_t xp_bytes = (size_t)BB * TT * 16 * sizeof(_Float16);  // 16 MiB
    _Float16* xpk = (_Float16*)((char*)d_ws + hs_bytes);

    if (ws_size >= hs_bytes + xp_bytes) {
        xpack_kernel<<<(BB * TT * 16) / 256, 256, 0, stream>>>(x, xpk);
        rnn_rec<true><<<32, 64, 0, stream>>>(x, xpk, W_ih, b_ih, W_hh, b_hh, hs, h_last);
    } else {
        rnn_rec<false><<<32, 64, 0, stream>>>(x, nullptr, W_ih, b_ih, W_hh, b_hh, hs, h_last);
    }
    rnn_decode<<<8192, 256, 0, stream>>>(hs, W_dec, b_dec, out);
}

// Round 4
// 299.728 us; speedup vs baseline: 1.8339x; 1.8339x over previous
//
#include <hip/hip_runtime.h>
#include <hip/hip_fp16.h>
#include <stdint.h>

#define BB 512
#define TT 1024
#define II 15
#define HH 64
#define OO 11

typedef __fp16 half2v __attribute__((ext_vector_type(2)));
typedef _Float16 half8 __attribute__((ext_vector_type(8)));
typedef float floatx4 __attribute__((ext_vector_type(4)));

union I2H { int i; half2v h; float f; };

__device__ __forceinline__ half2v bc_h2(int x) { I2H u; u.i = x; return u.h; }
__device__ __forceinline__ int bc_i(half2v x) { I2H u; u.h = x; return u.i; }

#if __has_builtin(__builtin_amdgcn_fdot2)
__device__ __forceinline__ float FDOT2(half2v a, half2v b, float c) {
    return __builtin_amdgcn_fdot2(a, b, c, false);
}
#else
__device__ __forceinline__ float FDOT2(half2v a, half2v b, float c) {
    return c + (float)a[0] * (float)b[0] + (float)a[1] * (float)b[1];
}
#endif

__device__ __forceinline__ float lane_xor1(float v) {
#if __has_builtin(__builtin_amdgcn_mov_dpp)
    I2H u; u.f = v;
    // quad_perm(1,0,3,2) = 0xB1 : lane -> lane^1
    u.i = __builtin_amdgcn_mov_dpp(u.i, 0xB1, 0xF, 0xF, false);
    return u.f;
#else
    return __shfl_xor(v, 1, 64);
#endif
}

// One wave per batch. lane = h_out index. W_hh row packed as 32 f16 pairs.
// Per step: pack h into f16 pairs (dpp + pkrtz), 32 readlane + 32 v_dot2_f32_f16
// for the GEMV, 7 pair-dots + 1 scalar fmac for the input proj (bias exact in
// f32 acc init). No barriers, no LDS. ~85 insts/step vs R1's ~170.
__global__ __launch_bounds__(64) void rnn_rec(
    const float* __restrict__ x, const float* __restrict__ W_ih,
    const float* __restrict__ b_ih, const float* __restrict__ W_hh,
    const float* __restrict__ b_hh, _Float16* __restrict__ hs,
    float* __restrict__ h_last)
{
    const int b = blockIdx.x;
    const int lane = threadIdx.x;

    // packed recurrent weights: whh[j] = (W_hh[lane][2j], W_hh[lane][2j+1])
    half2v whh[32];
#pragma unroll
    for (int j = 0; j < 32; ++j)
        whh[j] = __builtin_amdgcn_cvt_pkrtz(W_hh[lane * HH + 2 * j],
                                            W_hh[lane * HH + 2 * j + 1]);
    // packed input weights (i=0..13); i=14 kept f32
    half2v wx[7];
#pragma unroll
    for (int j = 0; j < 7; ++j)
        wx[j] = __builtin_amdgcn_cvt_pkrtz(W_ih[lane * II + 2 * j],
                                           W_ih[lane * II + 2 * j + 1]);
    const float w14 = W_ih[lane * II + 14];
    const float bias = b_ih[lane] + b_hh[lane];

    const float* xb = x + (size_t)b * TT * II;
    _Float16* hrow = hs + (size_t)b * TT * HH + lane;

    // stage chunk 0: lane L holds x[b][L][0..14]
    float cf[II];
#pragma unroll
    for (int i = 0; i < II; ++i) cf[i] = xb[lane * II + i];
    int xpi[7]; int x14i;
#pragma unroll
    for (int j = 0; j < 7; ++j)
        xpi[j] = bc_i(__builtin_amdgcn_cvt_pkrtz(cf[2 * j], cf[2 * j + 1]));
    { I2H u; u.f = cf[14]; x14i = u.i; }

    float h = 0.0f;

    for (int tc = 0; tc < TT; tc += 64) {
        // prefetch next chunk (redundant reload of current on the last chunk)
        const int tnb = (tc + 64 < TT) ? (tc + 64) : tc;
        float nf[II];
#pragma unroll
        for (int i = 0; i < II; ++i) nf[i] = xb[(tnb + lane) * II + i];

#pragma unroll 4
        for (int ts = 0; ts < 64; ++ts) {
            // pack h_{t-1} pairs: lane o -> (h[o], h[o^1]); even lanes hold pairs
            const float hn = lane_xor1(h);
            const int hpki = bc_i(__builtin_amdgcn_cvt_pkrtz(h, hn));

            float a0 = bias, a1 = 0.0f, a2 = 0.0f, a3 = 0.0f;
            // input projection (independent of h -> overlaps the h pack)
            a0 = FDOT2(bc_h2(__builtin_amdgcn_readlane(xpi[0], ts)), wx[0], a0);
            a1 = FDOT2(bc_h2(__builtin_amdgcn_readlane(xpi[1], ts)), wx[1], a1);
            a2 = FDOT2(bc_h2(__builtin_amdgcn_readlane(xpi[2], ts)), wx[2], a2);
            a3 = FDOT2(bc_h2(__builtin_amdgcn_readlane(xpi[3], ts)), wx[3], a3);
            a0 = FDOT2(bc_h2(__builtin_amdgcn_readlane(xpi[4], ts)), wx[4], a0);
            a1 = FDOT2(bc_h2(__builtin_amdgcn_readlane(xpi[5], ts)), wx[5], a1);
            a2 = FDOT2(bc_h2(__builtin_amdgcn_readlane(xpi[6], ts)), wx[6], a2);
            {
                I2H u; u.i = __builtin_amdgcn_readlane(x14i, ts);
                a3 = fmaf(u.f, w14, a3);
            }
            // recurrent GEMV: 32 pair-broadcasts (constant lane idx) + 32 dot2
#pragma unroll
            for (int j = 0; j < 32; ++j) {
                const int hb = __builtin_amdgcn_readlane(hpki, 2 * j);
                float& acc = (j & 3) == 0 ? a0 : (j & 3) == 1 ? a1
                           : (j & 3) == 2 ? a2 : a3;
                acc = FDOT2(bc_h2(hb), whh[j], acc);
            }
            h = fmaxf((a0 + a1) + (a2 + a3), 0.0f);
            hrow[(size_t)(tc + ts) * HH] = (_Float16)h;
        }

        // commit prefetched chunk
#pragma unroll
        for (int j = 0; j < 7; ++j)
            xpi[j] = bc_i(__builtin_amdgcn_cvt_pkrtz(nf[2 * j], nf[2 * j + 1]));
        { I2H u; u.f = nf[14]; x14i = u.i; }
    }
    h_last[b * HH + lane] = h;
}

// Decoder: one 16x16x64 tile per wave (16 consecutive (b,t) rows of one batch).
// hs read: 2KB contiguous per wave; out store: 704B contiguous per tile.
__global__ __launch_bounds__(256) void rnn_decode(
    const _Float16* __restrict__ hs, const float* __restrict__ W_dec,
    const float* __restrict__ b_dec, float* __restrict__ out)
{
    __shared__ __align__(16) _Float16 wl[16 * HH];
    const int tid = threadIdx.x;
    for (int i = tid; i < 16 * HH; i += 256)
        wl[i] = (_Float16)((i < OO * HH) ? W_dec[i] : 0.0f);
    __syncthreads();

    const int lane = tid & 63;
    const int wid  = tid >> 6;
    const int col  = lane & 15;
    const int quad = lane >> 4;
    const float bd = (col < OO) ? b_dec[col] : 0.0f;

    half8 bf0 = *(const half8*)&wl[col * HH + quad * 8];
    half8 bf1 = *(const half8*)&wl[col * HH + 32 + quad * 8];

    const size_t tile = (size_t)blockIdx.x * 4 + wid;   // 0..32767
    const size_t btb = tile * 16;
    const _Float16* ap = hs + (btb + (size_t)col) * HH + quad * 8;
    half8 a0 = *(const half8*)ap;
    half8 a1 = *(const half8*)(ap + 32);

    floatx4 acc = {0.0f, 0.0f, 0.0f, 0.0f};
    acc = __builtin_amdgcn_mfma_f32_16x16x32_f16(a0, bf0, acc, 0, 0, 0);
    acc = __builtin_amdgcn_mfma_f32_16x16x32_f16(a1, bf1, acc, 0, 0, 0);

    if (col < OO) {
#pragma unroll
        for (int r = 0; r < 4; ++r) {
            const size_t row = btb + (size_t)(quad * 4 + r);
            out[row * OO + col] = fmaxf(acc[r] + bd, 0.0f);
        }
    }
}

extern "C" void kernel_launch(void* const* d_in, const int* in_sizes, int n_in,
                              void* d_out, int out_size, void* d_ws, size_t ws_size,
                              hipStream_t stream) {
    const float* x     = (const float*)d_in[0];
    const float* W_ih  = (const float*)d_in[1];
    const float* b_ih  = (const float*)d_in[2];
    const float* W_hh  = (const float*)d_in[3];
    const float* b_hh  = (const float*)d_in[4];
    const float* W_dec = (const float*)d_in[5];
    const float* b_dec = (const float*)d_in[6];

    float* out    = (float*)d_out;
    float* h_last = out + (size_t)BB * TT * OO;   // second tuple output
    _Float16* hs  = (_Float16*)d_ws;              // [B][T][H] f16, 64 MiB

    rnn_rec<<<BB, 64, 0, stream>>>(x, W_ih, b_ih, W_hh, b_hh, hs, h_last);
    rnn_decode<<<8192, 256, 0, stream>>>(hs, W_dec, b_dec, out);
}

// Round 5
// 276.192 us; speedup vs baseline: 1.9902x; 1.0852x over previous
//
#include <hip/hip_runtime.h>
#include <hip/hip_fp16.h>
#include <stdint.h>

#define BB 512
#define TT 1024
#define II 15
#define HH 64
#define OO 11

typedef __fp16 half2v __attribute__((ext_vector_type(2)));
typedef _Float16 half8 __attribute__((ext_vector_type(8)));
typedef float floatx4 __attribute__((ext_vector_type(4)));
typedef int int4v __attribute__((ext_vector_type(4)));

union PK { int i; half2v h; float f; };

__device__ __forceinline__ half2v i2h2(int v) { PK u; u.i = v; return u.h; }
__device__ __forceinline__ int h22i(half2v v) { PK u; u.h = v; return u.i; }

__device__ __forceinline__ float FDOT2(half2v a, half2v b, float c) {
    return __builtin_amdgcn_fdot2(a, b, c, false);
}

__device__ __forceinline__ float lane_xor1(float v) {
    PK u; u.f = v;
    // quad_perm(1,0,3,2) = 0xB1 : lane -> lane^1
    u.i = __builtin_amdgcn_mov_dpp(u.i, 0xB1, 0xF, 0xF, false);
    return u.f;
}

// One wave per batch, lane = h_out. All cross-lane broadcast goes through LDS
// (wave-synchronous, no barriers): h pairs written to hbuf each step, read
// back as 8 uniform-address ds_read_b128 (broadcast, conflict-free, LDS pipe
// not VALU). x packed per 64-step chunk into xbuf; 2 broadcast reads/step.
// Per-step VALU: 40 v_dot2_f32_f16 + pack + tail (~49 insts), zero readlanes.
__global__ __launch_bounds__(64) void rnn_rec(
    const float* __restrict__ x, const float* __restrict__ W_ih,
    const float* __restrict__ b_ih, const float* __restrict__ W_hh,
    const float* __restrict__ b_hh, _Float16* __restrict__ hs,
    float* __restrict__ h_last)
{
    __shared__ __align__(16) int xbuf[64 * 8];   // [step][8 packed pairs]
    __shared__ __align__(16) int hbuf[64];       // slots 0..31 = h pairs
    const int b = blockIdx.x;
    const int lane = threadIdx.x;

    // packed recurrent weights: whh[j] = (W_hh[lane][2j], W_hh[lane][2j+1])
    half2v whh[32];
#pragma unroll
    for (int j = 0; j < 32; ++j)
        whh[j] = __builtin_amdgcn_cvt_pkrtz(W_hh[lane * HH + 2 * j],
                                            W_hh[lane * HH + 2 * j + 1]);
    // packed input weights; pair 7 = (w14, bias) matching x pair (x14, 1.0)
    half2v wx[8];
#pragma unroll
    for (int j = 0; j < 7; ++j)
        wx[j] = __builtin_amdgcn_cvt_pkrtz(W_ih[lane * II + 2 * j],
                                           W_ih[lane * II + 2 * j + 1]);
    wx[7] = __builtin_amdgcn_cvt_pkrtz(W_ih[lane * II + 14],
                                       b_ih[lane] + b_hh[lane]);

    const float* xb = x + (size_t)b * TT * II;
    _Float16* hrow = hs + (size_t)b * TT * HH + lane;
    // even lanes fill slots 0..31 with good pairs; odd lanes park in 32..63
    const int hwslot = (lane >> 1) | ((lane & 1) << 5);

    // stage chunk 0: lane ts holds x[b][ts][0..14] -> 8 packed pairs in xbuf
    {
        float cf[II];
#pragma unroll
        for (int i = 0; i < II; ++i) cf[i] = xb[lane * II + i];
        int4v p0, p1;
        p0.x = h22i(__builtin_amdgcn_cvt_pkrtz(cf[0], cf[1]));
        p0.y = h22i(__builtin_amdgcn_cvt_pkrtz(cf[2], cf[3]));
        p0.z = h22i(__builtin_amdgcn_cvt_pkrtz(cf[4], cf[5]));
        p0.w = h22i(__builtin_amdgcn_cvt_pkrtz(cf[6], cf[7]));
        p1.x = h22i(__builtin_amdgcn_cvt_pkrtz(cf[8], cf[9]));
        p1.y = h22i(__builtin_amdgcn_cvt_pkrtz(cf[10], cf[11]));
        p1.z = h22i(__builtin_amdgcn_cvt_pkrtz(cf[12], cf[13]));
        p1.w = h22i(__builtin_amdgcn_cvt_pkrtz(cf[14], 1.0f));
        *(int4v*)&xbuf[lane * 8] = p0;
        *(int4v*)&xbuf[lane * 8 + 4] = p1;
    }

    float h = 0.0f;

    for (int tc = 0; tc < TT; tc += 64) {
        // prefetch next chunk of x into registers (consumed at chunk end)
        const int tnb = (tc + 64 < TT) ? (tc + 64) : tc;
        float nf[II];
#pragma unroll
        for (int i = 0; i < II; ++i)
            nf[i] = xb[(size_t)(tnb + lane) * II + i];

#pragma unroll 4
        for (int ts = 0; ts < 64; ++ts) {
            // pack (h[o], h[o^1]) and publish to LDS (2 lanes/bank = free)
            PK hp;
            hp.h = __builtin_amdgcn_cvt_pkrtz(h, lane_xor1(h));
            hbuf[hwslot] = hp.i;

            // broadcast reads (uniform address): x pairs + all 32 h pairs
            const int4v xv0 = *(const int4v*)&xbuf[ts * 8];
            const int4v xv1 = *(const int4v*)&xbuf[ts * 8 + 4];
            int4v hb[8];
#pragma unroll
            for (int q = 0; q < 8; ++q)
                hb[q] = *(const int4v*)&hbuf[q * 4];

            // input projection (independent -> fills the LDS latency window)
            float a0 = FDOT2(i2h2(xv0.x), wx[0], 0.0f);
            float a1 = FDOT2(i2h2(xv0.y), wx[1], 0.0f);
            float a2 = FDOT2(i2h2(xv0.z), wx[2], 0.0f);
            float a3 = FDOT2(i2h2(xv0.w), wx[3], 0.0f);
            a0 = FDOT2(i2h2(xv1.x), wx[4], a0);
            a1 = FDOT2(i2h2(xv1.y), wx[5], a1);
            a2 = FDOT2(i2h2(xv1.z), wx[6], a2);
            a3 = FDOT2(i2h2(xv1.w), wx[7], a3);
            // recurrent GEMV: 32 dot2, 4 independent chains
#pragma unroll
            for (int q = 0; q < 8; ++q) {
                a0 = FDOT2(i2h2(hb[q].x), whh[4 * q + 0], a0);
                a1 = FDOT2(i2h2(hb[q].y), whh[4 * q + 1], a1);
                a2 = FDOT2(i2h2(hb[q].z), whh[4 * q + 2], a2);
                a3 = FDOT2(i2h2(hb[q].w), whh[4 * q + 3], a3);
            }
            h = fmaxf((a0 + a1) + (a2 + a3), 0.0f);
            *hrow = (_Float16)h;      // 64 lanes x 2B contiguous = 128B
            hrow += HH;
        }

        // commit prefetched chunk into xbuf (in-order DS: next reads see it)
        int4v p0, p1;
        p0.x = h22i(__builtin_amdgcn_cvt_pkrtz(nf[0], nf[1]));
        p0.y = h22i(__builtin_amdgcn_cvt_pkrtz(nf[2], nf[3]));
        p0.z = h22i(__builtin_amdgcn_cvt_pkrtz(nf[4], nf[5]));
        p0.w = h22i(__builtin_amdgcn_cvt_pkrtz(nf[6], nf[7]));
        p1.x = h22i(__builtin_amdgcn_cvt_pkrtz(nf[8], nf[9]));
        p1.y = h22i(__builtin_amdgcn_cvt_pkrtz(nf[10], nf[11]));
        p1.z = h22i(__builtin_amdgcn_cvt_pkrtz(nf[12], nf[13]));
        p1.w = h22i(__builtin_amdgcn_cvt_pkrtz(nf[14], 1.0f));
        *(int4v*)&xbuf[lane * 8] = p0;
        *(int4v*)&xbuf[lane * 8 + 4] = p1;
    }
    h_last[b * HH + lane] = h;
}

// Decoder: one 16x16x64 tile per wave (16 consecutive (b,t) rows of one batch).
// hs read: 2KB contiguous per wave; out store: 704B contiguous per tile.
__global__ __launch_bounds__(256) void rnn_decode(
    const _Float16* __restrict__ hs, const float* __restrict__ W_dec,
    const float* __restrict__ b_dec, float* __restrict__ out)
{
    __shared__ __align__(16) _Float16 wl[16 * HH];
    const int tid = threadIdx.x;
    for (int i = tid; i < 16 * HH; i += 256)
        wl[i] = (_Float16)((i < OO * HH) ? W_dec[i] : 0.0f);
    __syncthreads();

    const int lane = tid & 63;
    const int wid  = tid >> 6;
    const int col  = lane & 15;
    const int quad = lane >> 4;
    const float bd = (col < OO) ? b_dec[col] : 0.0f;

    half8 bf0 = *(const half8*)&wl[col * HH + quad * 8];
    half8 bf1 = *(const half8*)&wl[col * HH + 32 + quad * 8];

    const size_t tile = (size_t)blockIdx.x * 4 + wid;   // 0..32767
    const size_t btb = tile * 16;
    const _Float16* ap = hs + (btb + (size_t)col) * HH + quad * 8;
    half8 a0 = *(const half8*)ap;
    half8 a1 = *(const half8*)(ap + 32);

    floatx4 acc = {0.0f, 0.0f, 0.0f, 0.0f};
    acc = __builtin_amdgcn_mfma_f32_16x16x32_f16(a0, bf0, acc, 0, 0, 0);
    acc = __builtin_amdgcn_mfma_f32_16x16x32_f16(a1, bf1, acc, 0, 0, 0);

    if (col < OO) {
#pragma unroll
        for (int r = 0; r < 4; ++r) {
            const size_t row = btb + (size_t)(quad * 4 + r);
            out[row * OO + col] = fmaxf(acc[r] + bd, 0.0f);
        }
    }
}

extern "C" void kernel_launch(void* const* d_in, const int* in_sizes, int n_in,
                              void* d_out, int out_size, void* d_ws, size_t ws_size,
                              hipStream_t stream) {
    const float* x     = (const float*)d_in[0];
    const float* W_ih  = (const float*)d_in[1];
    const float* b_ih  = (const float*)d_in[2];
    const float* W_hh  = (const float*)d_in[3];
    const float* b_hh  = (const float*)d_in[4];
    const float* W_dec = (const float*)d_in[5];
    const float* b_dec = (const float*)d_in[6];

    float* out    = (float*)d_out;
    float* h_last = out + (size_t)BB * TT * OO;   // second tuple output
    _Float16* hs  = (_Float16*)d_ws;              // [B][T][H] f16, 64 MiB

    rnn_rec<<<BB, 64, 0, stream>>>(x, W_ih, b_ih, W_hh, b_hh, hs, h_last);
    rnn_decode<<<8192, 256, 0, stream>>>(hs, W_dec, b_dec, out);
}